// Round 1
// baseline (724.061 us; speedup 1.0000x reference)
//
#include <hip/hip_runtime.h>
#include <hip/hip_bf16.h>
#include <cstdint>

// ---------- types ----------
typedef __bf16 bf16x8 __attribute__((ext_vector_type(8)));
typedef float  f32x4  __attribute__((ext_vector_type(4)));

typedef __attribute__((address_space(3))) void lds_void;
typedef const __attribute__((address_space(1))) void gbl_cvoid;

#define GLOAD_LDS16(g, l) \
    __builtin_amdgcn_global_load_lds((gbl_cvoid*)(g), (lds_void*)(l), 16, 0, 0)

// Problem constants
static constexpr int IN   = 4096;
static constexpr int OUT  = 4096;
static constexpr int RANK = 256;
static constexpr int M_ROWS = 4 * 2048;  // B*S = 8192

// ---------- kernel 1/2: fp32 -> bf16 cast (8 elems/thread) ----------
__global__ void cast_f32_bf16(const float* __restrict__ in, __bf16* __restrict__ out, int n8) {
    int t = blockIdx.x * blockDim.x + threadIdx.x;
    if (t >= n8) return;
    const float4* p = (const float4*)in + (size_t)t * 2;
    float4 v0 = p[0], v1 = p[1];
    bf16x8 o;
    o[0] = (__bf16)v0.x; o[1] = (__bf16)v0.y; o[2] = (__bf16)v0.z; o[3] = (__bf16)v0.w;
    o[4] = (__bf16)v1.x; o[5] = (__bf16)v1.y; o[6] = (__bf16)v1.z; o[7] = (__bf16)v1.w;
    ((bf16x8*)out)[t] = o;
}

// ---------- kernel 3: AdT[i][r] = bf16(d[r] * A[r][i]) ----------
// A: [RANK, IN] fp32 row-major; AdT: [IN, RANK] bf16 row-major (writes coalesced)
__global__ void make_adt(const float* __restrict__ A, const float* __restrict__ d,
                         __bf16* __restrict__ AdT) {
    int t = blockIdx.x * blockDim.x + threadIdx.x;   // 0 .. IN*RANK-1
    int r = t & (RANK - 1);
    int i = t >> 8;    // RANK = 256
    AdT[t] = (__bf16)(A[(size_t)r * IN + i] * d[r]);
}

// ---------- shared GEMM tile structure: 128x128 tile, BK=64, 256 threads ----------
// A-operand:  [M,K] bf16 row-major (K contiguous)
// B-operand:  [N,K] bf16 row-major (K contiguous)  (i.e. B^T form)
// Wave w: 64x64 quadrant (wm = (w>>1)*64, wn = (w&1)*64), 4x4 grid of 16x16x32 MFMA.
// C/D layout (verified m89/m91): col = lane&15, row = (lane>>4)*4 + reg.

// ---------- kernel 4: Weff[o][i] = bf16( W[o][i] + sum_r Bw[o][r]*AdT[i][r] ) ----------
__global__ __launch_bounds__(256) void weff_gemm(
    const __bf16* __restrict__ Bw,   // [OUT, RANK] bf16
    const __bf16* __restrict__ AdT,  // [IN,  RANK] bf16
    const float*  __restrict__ W,    // [OUT, IN] fp32
    __bf16* __restrict__ Weff)       // [OUT, IN] bf16
{
    constexpr int K = RANK;   // 256
    __shared__ __bf16 sA[128 * 64];
    __shared__ __bf16 sB[128 * 64];

    const int t    = threadIdx.x;
    const int wave = t >> 6;
    const int lane = t & 63;
    const int quad = lane >> 4;
    const int l16  = lane & 15;
    const int m0 = blockIdx.y * 128;   // o
    const int n0 = blockIdx.x * 128;   // i
    const int wm = (wave >> 1) * 64;
    const int wn = (wave & 1) * 64;

    f32x4 acc[4][4] = {};

    for (int kt = 0; kt < K; kt += 64) {
#pragma unroll
        for (int j = 0; j < 4; ++j) {
            int ci = j * 256 + t;         // 0..1023 chunk id (16B each)
            int row = ci >> 3;
            int kc  = ci & 7;
            GLOAD_LDS16(Bw  + (size_t)(m0 + row) * K + kt + kc * 8, sA + ci * 8);
        }
#pragma unroll
        for (int j = 0; j < 4; ++j) {
            int ci = j * 256 + t;
            int row = ci >> 3;
            int kc  = ci & 7;
            GLOAD_LDS16(AdT + (size_t)(n0 + row) * K + kt + kc * 8, sB + ci * 8);
        }
        __syncthreads();

#pragma unroll
        for (int kk = 0; kk < 64; kk += 32) {
            bf16x8 a[4], b[4];
#pragma unroll
            for (int mi = 0; mi < 4; ++mi)
                a[mi] = *(const bf16x8*)(sA + (wm + mi * 16 + l16) * 64 + kk + quad * 8);
#pragma unroll
            for (int ni = 0; ni < 4; ++ni)
                b[ni] = *(const bf16x8*)(sB + (wn + ni * 16 + l16) * 64 + kk + quad * 8);
#pragma unroll
            for (int mi = 0; mi < 4; ++mi)
#pragma unroll
                for (int ni = 0; ni < 4; ++ni)
                    acc[mi][ni] = __builtin_amdgcn_mfma_f32_16x16x32_bf16(a[mi], b[ni], acc[mi][ni], 0, 0, 0);
        }
        __syncthreads();
    }

#pragma unroll
    for (int mi = 0; mi < 4; ++mi) {
#pragma unroll
        for (int r = 0; r < 4; ++r) {
            int row = m0 + wm + mi * 16 + quad * 4 + r;
#pragma unroll
            for (int ni = 0; ni < 4; ++ni) {
                int col = n0 + wn + ni * 16 + l16;
                size_t idx = (size_t)row * IN + col;
                Weff[idx] = (__bf16)(acc[mi][ni][r] + W[idx]);
            }
        }
    }
}

// ---------- kernel 5: out[m][n] = sum_k X[m][k]*Weff[n][k] + bias[n] ----------
__global__ __launch_bounds__(256) void main_gemm(
    const __bf16* __restrict__ X,     // [M, K=IN] bf16
    const __bf16* __restrict__ Wf,    // [N=OUT, K=IN] bf16
    const float*  __restrict__ bias,  // [N]
    float* __restrict__ out)          // [M, N] fp32
{
    constexpr int K = IN;     // 4096
    constexpr int N = OUT;    // 4096
    __shared__ __bf16 sA[128 * 64];
    __shared__ __bf16 sB[128 * 64];

    const int t    = threadIdx.x;
    const int wave = t >> 6;
    const int lane = t & 63;
    const int quad = lane >> 4;
    const int l16  = lane & 15;
    const int m0 = blockIdx.y * 128;
    const int n0 = blockIdx.x * 128;
    const int wm = (wave >> 1) * 64;
    const int wn = (wave & 1) * 64;

    f32x4 acc[4][4] = {};

    for (int kt = 0; kt < K; kt += 64) {
#pragma unroll
        for (int j = 0; j < 4; ++j) {
            int ci = j * 256 + t;
            int row = ci >> 3;
            int kc  = ci & 7;
            GLOAD_LDS16(X  + (size_t)(m0 + row) * K + kt + kc * 8, sA + ci * 8);
        }
#pragma unroll
        for (int j = 0; j < 4; ++j) {
            int ci = j * 256 + t;
            int row = ci >> 3;
            int kc  = ci & 7;
            GLOAD_LDS16(Wf + (size_t)(n0 + row) * K + kt + kc * 8, sB + ci * 8);
        }
        __syncthreads();

#pragma unroll
        for (int kk = 0; kk < 64; kk += 32) {
            bf16x8 a[4], b[4];
#pragma unroll
            for (int mi = 0; mi < 4; ++mi)
                a[mi] = *(const bf16x8*)(sA + (wm + mi * 16 + l16) * 64 + kk + quad * 8);
#pragma unroll
            for (int ni = 0; ni < 4; ++ni)
                b[ni] = *(const bf16x8*)(sB + (wn + ni * 16 + l16) * 64 + kk + quad * 8);
#pragma unroll
            for (int mi = 0; mi < 4; ++mi)
#pragma unroll
                for (int ni = 0; ni < 4; ++ni)
                    acc[mi][ni] = __builtin_amdgcn_mfma_f32_16x16x32_bf16(a[mi], b[ni], acc[mi][ni], 0, 0, 0);
        }
        __syncthreads();
    }

    // epilogue: + bias, fp32 store (coalesced along n)
    float bv[4];
#pragma unroll
    for (int ni = 0; ni < 4; ++ni)
        bv[ni] = bias[n0 + wn + ni * 16 + l16];

#pragma unroll
    for (int mi = 0; mi < 4; ++mi) {
#pragma unroll
        for (int r = 0; r < 4; ++r) {
            int row = m0 + wm + mi * 16 + quad * 4 + r;
#pragma unroll
            for (int ni = 0; ni < 4; ++ni) {
                int col = n0 + wn + ni * 16 + l16;
                out[(size_t)row * N + col] = acc[mi][ni][r] + bv[ni];
            }
        }
    }
}

// ---------- launch ----------
extern "C" void kernel_launch(void* const* d_in, const int* in_sizes, int n_in,
                              void* d_out, int out_size, void* d_ws, size_t ws_size,
                              hipStream_t stream) {
    const float* x  = (const float*)d_in[0];   // [8192, 4096]
    const float* W  = (const float*)d_in[1];   // [4096, 4096]
    const float* A  = (const float*)d_in[2];   // [256, 4096]
    const float* Bm = (const float*)d_in[3];   // [4096, 256]
    const float* d  = (const float*)d_in[4];   // [256]
    const float* b  = (const float*)d_in[5];   // [4096]
    float* out = (float*)d_out;

    // workspace layout
    char* ws = (char*)d_ws;
    __bf16* x_bf   = (__bf16*)(ws);                                  // 67,108,864 B
    __bf16* weff   = (__bf16*)(ws + (size_t)67108864);               // 33,554,432 B
    __bf16* b_bf   = (__bf16*)(ws + (size_t)67108864 + 33554432);    //  2,097,152 B
    __bf16* adt_bf = (__bf16*)(ws + (size_t)67108864 + 33554432 + 2097152); // 2,097,152 B

    // 1) cast x -> bf16 : 33,554,432 elems / 8 = 4,194,304 threads
    cast_f32_bf16<<<4194304 / 256, 256, 0, stream>>>(x, x_bf, 4194304);
    // 2) cast B -> bf16 : 1,048,576 / 8 = 131,072 threads
    cast_f32_bf16<<<131072 / 256, 256, 0, stream>>>(Bm, b_bf, 131072);
    // 3) AdT[i][r] = d[r]*A[r][i]
    make_adt<<<(IN * RANK) / 256, 256, 0, stream>>>(A, d, adt_bf);
    // 4) Weff = W + B diag(d) A   (grid: N-tiles x M-tiles = 32x32)
    weff_gemm<<<dim3(IN / 128, OUT / 128), 256, 0, stream>>>(b_bf, adt_bf, W, weff);
    // 5) out = x_bf @ Weff^T + b  (grid: 32 x 64)
    main_gemm<<<dim3(OUT / 128, M_ROWS / 128), 256, 0, stream>>>(x_bf, weff, b, out);
}

// Round 2
// 675.040 us; speedup vs baseline: 1.0726x; 1.0726x over previous
//
#include <hip/hip_runtime.h>
#include <hip/hip_bf16.h>
#include <cstdint>

// ---------- types ----------
typedef __bf16 bf16x8 __attribute__((ext_vector_type(8)));
typedef float  f32x4  __attribute__((ext_vector_type(4)));

typedef __attribute__((address_space(3))) void lds_void;
typedef const __attribute__((address_space(1))) void gbl_cvoid;

#define GLOAD_LDS16(g, l) \
    __builtin_amdgcn_global_load_lds((gbl_cvoid*)(g), (lds_void*)(l), 16, 0, 0)

// Problem constants
static constexpr int IN   = 4096;
static constexpr int OUT  = 4096;
static constexpr int RANK = 256;
static constexpr int M_ROWS = 4 * 2048;  // B*S = 8192

// ---------- fp32 -> bf16 cast (8 elems/thread) ----------
__global__ void cast_f32_bf16(const float* __restrict__ in, __bf16* __restrict__ out, int n8) {
    int t = blockIdx.x * blockDim.x + threadIdx.x;
    if (t >= n8) return;
    const float4* p = (const float4*)in + (size_t)t * 2;
    float4 v0 = p[0], v1 = p[1];
    bf16x8 o;
    o[0] = (__bf16)v0.x; o[1] = (__bf16)v0.y; o[2] = (__bf16)v0.z; o[3] = (__bf16)v0.w;
    o[4] = (__bf16)v1.x; o[5] = (__bf16)v1.y; o[6] = (__bf16)v1.z; o[7] = (__bf16)v1.w;
    ((bf16x8*)out)[t] = o;
}

// ---------- AdT[i][r] = bf16(d[r] * A[r][i]) via LDS tile transpose ----------
// A: [RANK, IN] fp32; AdT: [IN, RANK] bf16. Both read and write coalesced.
// Grid: (IN/64) x (RANK/64) blocks of 256 threads; 64x64 tile (+1 pad).
__global__ __launch_bounds__(256) void make_adt(const float* __restrict__ A,
                                                const float* __restrict__ d,
                                                __bf16* __restrict__ AdT) {
    __shared__ float tile[64][65];
    const int t  = threadIdx.x;
    const int i0 = blockIdx.x * 64;
    const int r0 = blockIdx.y * 64;
    const int cl = t & 63;   // lane within row-segment
    const int rw = t >> 6;   // 0..3

#pragma unroll
    for (int it = 0; it < 16; ++it) {
        int rl = it * 4 + rw;                         // A-row local
        tile[rl][cl] = A[(size_t)(r0 + rl) * IN + i0 + cl];
    }
    __syncthreads();
    float dv = d[r0 + cl];
#pragma unroll
    for (int it = 0; it < 16; ++it) {
        int il = it * 4 + rw;                         // out-row local (i)
        AdT[(size_t)(i0 + il) * RANK + r0 + cl] = (__bf16)(tile[cl][il] * dv);
    }
}

// ---------- GEMM tile structure: 128x128 tile, BK=64, 256 threads ----------
// LDS layout XOR-swizzled at 16B-chunk granularity: chunk (row, kc) lives at
// slot (kc ^ (row&7)). global_load_lds dst stays lane-contiguous (required);
// the global SOURCE address is permuted per-lane (same 128B segment -> still
// coalesced). Fragment reads then spread each served octet across all 8
// bank-groups -> conflict-free ds_read_b128.
// C/D layout (verified m89/m91): col = lane&15, row = (lane>>4)*4 + reg.

// ---------- Weff[o][i] = bf16( W[o][i] + sum_r Bw[o][r]*AdT[i][r] ) ----------
__global__ __launch_bounds__(256) void weff_gemm(
    const __bf16* __restrict__ Bw,   // [OUT, RANK] bf16
    const __bf16* __restrict__ AdT,  // [IN,  RANK] bf16
    const float*  __restrict__ W,    // [OUT, IN] fp32
    __bf16* __restrict__ Weff)       // [OUT, IN] bf16
{
    constexpr int K = RANK;   // 256
    __shared__ __bf16 sA[128 * 64];
    __shared__ __bf16 sB[128 * 64];

    const int t    = threadIdx.x;
    const int wave = t >> 6;
    const int lane = t & 63;
    const int quad = lane >> 4;
    const int l16  = lane & 15;
    const int m0 = blockIdx.y * 128;   // o
    const int n0 = blockIdx.x * 128;   // i
    const int wm = (wave >> 1) * 64;
    const int wn = (wave & 1) * 64;
    const int xr = l16 & 7;            // fragment-read xor term

    f32x4 acc[4][4] = {};

    for (int kt = 0; kt < K; kt += 64) {
#pragma unroll
        for (int j = 0; j < 4; ++j) {
            int ci  = j * 256 + t;
            int row = ci >> 3;
            int kc  = (ci & 7) ^ (row & 7);   // swizzled source chunk
            GLOAD_LDS16(Bw  + (size_t)(m0 + row) * K + kt + kc * 8, sA + ci * 8);
        }
#pragma unroll
        for (int j = 0; j < 4; ++j) {
            int ci  = j * 256 + t;
            int row = ci >> 3;
            int kc  = (ci & 7) ^ (row & 7);
            GLOAD_LDS16(AdT + (size_t)(n0 + row) * K + kt + kc * 8, sB + ci * 8);
        }
        __syncthreads();

#pragma unroll
        for (int kk = 0; kk < 64; kk += 32) {
            const int kb = kk >> 3;           // 0 or 4
            bf16x8 a[4], b[4];
#pragma unroll
            for (int mi = 0; mi < 4; ++mi)
                a[mi] = *(const bf16x8*)(sA + (wm + mi * 16 + l16) * 64 + (((kb + quad) ^ xr) << 3));
#pragma unroll
            for (int ni = 0; ni < 4; ++ni)
                b[ni] = *(const bf16x8*)(sB + (wn + ni * 16 + l16) * 64 + (((kb + quad) ^ xr) << 3));
#pragma unroll
            for (int mi = 0; mi < 4; ++mi)
#pragma unroll
                for (int ni = 0; ni < 4; ++ni)
                    acc[mi][ni] = __builtin_amdgcn_mfma_f32_16x16x32_bf16(a[mi], b[ni], acc[mi][ni], 0, 0, 0);
        }
        __syncthreads();
    }

#pragma unroll
    for (int mi = 0; mi < 4; ++mi) {
#pragma unroll
        for (int r = 0; r < 4; ++r) {
            int row = m0 + wm + mi * 16 + quad * 4 + r;
#pragma unroll
            for (int ni = 0; ni < 4; ++ni) {
                int col = n0 + wn + ni * 16 + l16;
                size_t idx = (size_t)row * IN + col;
                Weff[idx] = (__bf16)(acc[mi][ni][r] + W[idx]);
            }
        }
    }
}

// ---------- out[m][n] = sum_k X[m][k]*Weff[n][k] + bias[n] ----------
__global__ __launch_bounds__(256) void main_gemm(
    const __bf16* __restrict__ X,     // [M, K=IN] bf16
    const __bf16* __restrict__ Wf,    // [N=OUT, K=IN] bf16
    const float*  __restrict__ bias,  // [N]
    float* __restrict__ out)          // [M, N] fp32
{
    constexpr int K = IN;     // 4096
    constexpr int N = OUT;    // 4096
    __shared__ __bf16 sA[128 * 64];
    __shared__ __bf16 sB[128 * 64];

    const int t    = threadIdx.x;
    const int wave = t >> 6;
    const int lane = t & 63;
    const int quad = lane >> 4;
    const int l16  = lane & 15;
    const int m0 = blockIdx.y * 128;
    const int n0 = blockIdx.x * 128;
    const int wm = (wave >> 1) * 64;
    const int wn = (wave & 1) * 64;
    const int xr = l16 & 7;

    f32x4 acc[4][4] = {};

    for (int kt = 0; kt < K; kt += 64) {
#pragma unroll
        for (int j = 0; j < 4; ++j) {
            int ci  = j * 256 + t;
            int row = ci >> 3;
            int kc  = (ci & 7) ^ (row & 7);
            GLOAD_LDS16(X  + (size_t)(m0 + row) * K + kt + kc * 8, sA + ci * 8);
        }
#pragma unroll
        for (int j = 0; j < 4; ++j) {
            int ci  = j * 256 + t;
            int row = ci >> 3;
            int kc  = (ci & 7) ^ (row & 7);
            GLOAD_LDS16(Wf + (size_t)(n0 + row) * K + kt + kc * 8, sB + ci * 8);
        }
        __syncthreads();

#pragma unroll
        for (int kk = 0; kk < 64; kk += 32) {
            const int kb = kk >> 3;
            bf16x8 a[4], b[4];
#pragma unroll
            for (int mi = 0; mi < 4; ++mi)
                a[mi] = *(const bf16x8*)(sA + (wm + mi * 16 + l16) * 64 + (((kb + quad) ^ xr) << 3));
#pragma unroll
            for (int ni = 0; ni < 4; ++ni)
                b[ni] = *(const bf16x8*)(sB + (wn + ni * 16 + l16) * 64 + (((kb + quad) ^ xr) << 3));
#pragma unroll
            for (int mi = 0; mi < 4; ++mi)
#pragma unroll
                for (int ni = 0; ni < 4; ++ni)
                    acc[mi][ni] = __builtin_amdgcn_mfma_f32_16x16x32_bf16(a[mi], b[ni], acc[mi][ni], 0, 0, 0);
        }
        __syncthreads();
    }

    // epilogue: + bias, fp32 store (coalesced along n)
    float bv[4];
#pragma unroll
    for (int ni = 0; ni < 4; ++ni)
        bv[ni] = bias[n0 + wn + ni * 16 + l16];

#pragma unroll
    for (int mi = 0; mi < 4; ++mi) {
#pragma unroll
        for (int r = 0; r < 4; ++r) {
            int row = m0 + wm + mi * 16 + quad * 4 + r;
#pragma unroll
            for (int ni = 0; ni < 4; ++ni) {
                int col = n0 + wn + ni * 16 + l16;
                out[(size_t)row * N + col] = acc[mi][ni][r] + bv[ni];
            }
        }
    }
}

// ---------- launch ----------
extern "C" void kernel_launch(void* const* d_in, const int* in_sizes, int n_in,
                              void* d_out, int out_size, void* d_ws, size_t ws_size,
                              hipStream_t stream) {
    const float* x  = (const float*)d_in[0];   // [8192, 4096]
    const float* W  = (const float*)d_in[1];   // [4096, 4096]
    const float* A  = (const float*)d_in[2];   // [256, 4096]
    const float* Bm = (const float*)d_in[3];   // [4096, 256]
    const float* d  = (const float*)d_in[4];   // [256]
    const float* b  = (const float*)d_in[5];   // [4096]
    float* out = (float*)d_out;

    // workspace layout
    char* ws = (char*)d_ws;
    __bf16* x_bf   = (__bf16*)(ws);                                  // 67,108,864 B
    __bf16* weff   = (__bf16*)(ws + (size_t)67108864);               // 33,554,432 B
    __bf16* b_bf   = (__bf16*)(ws + (size_t)67108864 + 33554432);    //  2,097,152 B
    __bf16* adt_bf = (__bf16*)(ws + (size_t)67108864 + 33554432 + 2097152); // 2,097,152 B

    // 1) cast x -> bf16
    cast_f32_bf16<<<4194304 / 256, 256, 0, stream>>>(x, x_bf, 4194304);
    // 2) cast B -> bf16
    cast_f32_bf16<<<131072 / 256, 256, 0, stream>>>(Bm, b_bf, 131072);
    // 3) AdT[i][r] = d[r]*A[r][i]  (coalesced transpose)
    make_adt<<<dim3(IN / 64, RANK / 64), 256, 0, stream>>>(A, d, adt_bf);
    // 4) Weff = W + B diag(d) A
    weff_gemm<<<dim3(IN / 128, OUT / 128), 256, 0, stream>>>(b_bf, adt_bf, W, weff);
    // 5) out = x_bf @ Weff^T + b
    main_gemm<<<dim3(OUT / 128, M_ROWS / 128), 256, 0, stream>>>(x_bf, weff, b, out);
}

// Round 3
// 620.445 us; speedup vs baseline: 1.1670x; 1.0880x over previous
//
#include <hip/hip_runtime.h>
#include <hip/hip_bf16.h>
#include <cstdint>

// ---------- types ----------
typedef __bf16 bf16x8 __attribute__((ext_vector_type(8)));
typedef float  f32x4  __attribute__((ext_vector_type(4)));

typedef __attribute__((address_space(3))) void lds_void;
typedef const __attribute__((address_space(1))) void gbl_cvoid;

#define GLOAD_LDS16(g, l) \
    __builtin_amdgcn_global_load_lds((gbl_cvoid*)(g), (lds_void*)(l), 16, 0, 0)

// Problem constants
static constexpr int IN   = 4096;
static constexpr int OUT  = 4096;
static constexpr int RANK = 256;
static constexpr int M_ROWS = 4 * 2048;  // B*S = 8192

// ---------- device helpers ----------
__device__ __forceinline__ void cast8(const float* __restrict__ in,
                                      __bf16* __restrict__ out, int t) {
    const float4* p = (const float4*)in + (size_t)t * 2;
    float4 v0 = p[0], v1 = p[1];
    bf16x8 o;
    o[0] = (__bf16)v0.x; o[1] = (__bf16)v0.y; o[2] = (__bf16)v0.z; o[3] = (__bf16)v0.w;
    o[4] = (__bf16)v1.x; o[5] = (__bf16)v1.y; o[6] = (__bf16)v1.z; o[7] = (__bf16)v1.w;
    ((bf16x8*)out)[t] = o;
}

// ---------- kernel 1: prep = cast B (blocks 0..511) + make AdT (blocks 512..767) ----
// AdT[i][r] = bf16(d[r] * A[r][i]) via 64x64 LDS tile transpose (both sides coalesced)
__global__ __launch_bounds__(256) void prep(
    const float* __restrict__ Bm, __bf16* __restrict__ Bbf,
    const float* __restrict__ A,  const float* __restrict__ d,
    __bf16* __restrict__ AdT)
{
    __shared__ float tile[64][65];
    const int blk = blockIdx.x;
    const int t   = threadIdx.x;

    if (blk < 512) {                     // cast B: 1,048,576 elems / 8
        cast8(Bm, Bbf, blk * 256 + t);
        return;
    }
    const int ab = blk - 512;            // 0..255
    const int i0 = (ab & 63) * 64;
    const int r0 = (ab >> 6) * 64;
    const int cl = t & 63;
    const int rw = t >> 6;

#pragma unroll
    for (int it = 0; it < 16; ++it) {
        int rl = it * 4 + rw;
        tile[rl][cl] = A[(size_t)(r0 + rl) * IN + i0 + cl];
    }
    __syncthreads();
    float dv = d[r0 + cl];
#pragma unroll
    for (int it = 0; it < 16; ++it) {
        int il = it * 4 + rw;
        AdT[(size_t)(i0 + il) * RANK + r0 + cl] = (__bf16)(tile[cl][il] * dv);
    }
}

// ---------- GEMM tile structure: 128x128 tile, BK=64, 256 threads ----------
// LDS XOR-swizzle at 16B-chunk granularity: chunk (row,kc) -> slot (kc ^ (row&7)).
// global_load_lds dst stays lane-contiguous; global SOURCE is permuted per-lane
// within the same 128B segment (coalescing preserved). Fragment ds_read_b128
// octets then hit all 8 bank-groups -> 0 conflicts (verified R2).
// C/D layout (verified m89/m91): col = lane&15, row = (lane>>4)*4 + reg.

// ---------- kernel 2: fused Weff-GEMM (blocks 0..1023) + cast x (blocks 1024..17407) --
// Weff[o][i] = bf16( W[o][i] + sum_r Bw[o][r]*AdT[i][r] )
// Fusion rationale: weff is MFMA/LDS-bound, cast_x is pure HBM BW -> co-scheduling
// overlaps the two (same-stream dispatches would serialize).
__global__ __launch_bounds__(256) void weff_cast(
    const __bf16* __restrict__ Bw,   // [OUT, RANK] bf16
    const __bf16* __restrict__ AdT,  // [IN,  RANK] bf16
    const float*  __restrict__ W,    // [OUT, IN] fp32
    __bf16* __restrict__ Weff,       // [OUT, IN] bf16
    const float*  __restrict__ x,    // [8192, 4096] fp32
    __bf16* __restrict__ x_bf)       // [8192, 4096] bf16
{
    __shared__ __bf16 sA[128 * 64];
    __shared__ __bf16 sB[128 * 64];

    const int blk = blockIdx.x;
    const int t   = threadIdx.x;

    if (blk >= 1024) {                   // cast x: 33,554,432 elems / 8
        cast8(x, x_bf, (blk - 1024) * 256 + t);
        return;
    }

    constexpr int K = RANK;   // 256
    const int wave = t >> 6;
    const int lane = t & 63;
    const int quad = lane >> 4;
    const int l16  = lane & 15;
    const int m0 = (blk >> 5) * 128;   // o
    const int n0 = (blk & 31) * 128;   // i
    const int wm = (wave >> 1) * 64;
    const int wn = (wave & 1) * 64;
    const int xr = l16 & 7;

    f32x4 acc[4][4] = {};

    for (int kt = 0; kt < K; kt += 64) {
#pragma unroll
        for (int j = 0; j < 4; ++j) {
            int ci  = j * 256 + t;
            int row = ci >> 3;
            int kc  = (ci & 7) ^ (row & 7);
            GLOAD_LDS16(Bw  + (size_t)(m0 + row) * K + kt + kc * 8, sA + ci * 8);
        }
#pragma unroll
        for (int j = 0; j < 4; ++j) {
            int ci  = j * 256 + t;
            int row = ci >> 3;
            int kc  = (ci & 7) ^ (row & 7);
            GLOAD_LDS16(AdT + (size_t)(n0 + row) * K + kt + kc * 8, sB + ci * 8);
        }
        __syncthreads();

#pragma unroll
        for (int kk = 0; kk < 64; kk += 32) {
            const int kb = kk >> 3;
            bf16x8 a[4], b[4];
#pragma unroll
            for (int mi = 0; mi < 4; ++mi)
                a[mi] = *(const bf16x8*)(sA + (wm + mi * 16 + l16) * 64 + (((kb + quad) ^ xr) << 3));
#pragma unroll
            for (int ni = 0; ni < 4; ++ni)
                b[ni] = *(const bf16x8*)(sB + (wn + ni * 16 + l16) * 64 + (((kb + quad) ^ xr) << 3));
#pragma unroll
            for (int mi = 0; mi < 4; ++mi)
#pragma unroll
                for (int ni = 0; ni < 4; ++ni)
                    acc[mi][ni] = __builtin_amdgcn_mfma_f32_16x16x32_bf16(a[mi], b[ni], acc[mi][ni], 0, 0, 0);
        }
        __syncthreads();
    }

#pragma unroll
    for (int mi = 0; mi < 4; ++mi) {
#pragma unroll
        for (int r = 0; r < 4; ++r) {
            int row = m0 + wm + mi * 16 + quad * 4 + r;
#pragma unroll
            for (int ni = 0; ni < 4; ++ni) {
                int col = n0 + wn + ni * 16 + l16;
                size_t idx = (size_t)row * IN + col;
                Weff[idx] = (__bf16)(acc[mi][ni][r] + W[idx]);
            }
        }
    }
}

// ---------- kernel 3: out[m][n] = sum_k X[m][k]*Weff[n][k] + bias[n] ----------
__global__ __launch_bounds__(256) void main_gemm(
    const __bf16* __restrict__ X,     // [M, K=IN] bf16
    const __bf16* __restrict__ Wf,    // [N=OUT, K=IN] bf16
    const float*  __restrict__ bias,  // [N]
    float* __restrict__ out)          // [M, N] fp32
{
    constexpr int K = IN;     // 4096
    constexpr int N = OUT;    // 4096
    __shared__ __bf16 sA[128 * 64];
    __shared__ __bf16 sB[128 * 64];

    const int t    = threadIdx.x;
    const int wave = t >> 6;
    const int lane = t & 63;
    const int quad = lane >> 4;
    const int l16  = lane & 15;
    const int m0 = blockIdx.y * 128;
    const int n0 = blockIdx.x * 128;
    const int wm = (wave >> 1) * 64;
    const int wn = (wave & 1) * 64;
    const int xr = l16 & 7;

    f32x4 acc[4][4] = {};

    for (int kt = 0; kt < K; kt += 64) {
#pragma unroll
        for (int j = 0; j < 4; ++j) {
            int ci  = j * 256 + t;
            int row = ci >> 3;
            int kc  = (ci & 7) ^ (row & 7);
            GLOAD_LDS16(X  + (size_t)(m0 + row) * K + kt + kc * 8, sA + ci * 8);
        }
#pragma unroll
        for (int j = 0; j < 4; ++j) {
            int ci  = j * 256 + t;
            int row = ci >> 3;
            int kc  = (ci & 7) ^ (row & 7);
            GLOAD_LDS16(Wf + (size_t)(n0 + row) * K + kt + kc * 8, sB + ci * 8);
        }
        __syncthreads();

#pragma unroll
        for (int kk = 0; kk < 64; kk += 32) {
            const int kb = kk >> 3;
            bf16x8 a[4], b[4];
#pragma unroll
            for (int mi = 0; mi < 4; ++mi)
                a[mi] = *(const bf16x8*)(sA + (wm + mi * 16 + l16) * 64 + (((kb + quad) ^ xr) << 3));
#pragma unroll
            for (int ni = 0; ni < 4; ++ni)
                b[ni] = *(const bf16x8*)(sB + (wn + ni * 16 + l16) * 64 + (((kb + quad) ^ xr) << 3));
#pragma unroll
            for (int mi = 0; mi < 4; ++mi)
#pragma unroll
                for (int ni = 0; ni < 4; ++ni)
                    acc[mi][ni] = __builtin_amdgcn_mfma_f32_16x16x32_bf16(a[mi], b[ni], acc[mi][ni], 0, 0, 0);
        }
        __syncthreads();
    }

    float bv[4];
#pragma unroll
    for (int ni = 0; ni < 4; ++ni)
        bv[ni] = bias[n0 + wn + ni * 16 + l16];

#pragma unroll
    for (int mi = 0; mi < 4; ++mi) {
#pragma unroll
        for (int r = 0; r < 4; ++r) {
            int row = m0 + wm + mi * 16 + quad * 4 + r;
#pragma unroll
            for (int ni = 0; ni < 4; ++ni) {
                int col = n0 + wn + ni * 16 + l16;
                out[(size_t)row * N + col] = acc[mi][ni][r] + bv[ni];
            }
        }
    }
}

// ---------- launch ----------
extern "C" void kernel_launch(void* const* d_in, const int* in_sizes, int n_in,
                              void* d_out, int out_size, void* d_ws, size_t ws_size,
                              hipStream_t stream) {
    const float* x  = (const float*)d_in[0];   // [8192, 4096]
    const float* W  = (const float*)d_in[1];   // [4096, 4096]
    const float* A  = (const float*)d_in[2];   // [256, 4096]
    const float* Bm = (const float*)d_in[3];   // [4096, 256]
    const float* d  = (const float*)d_in[4];   // [256]
    const float* b  = (const float*)d_in[5];   // [4096]
    float* out = (float*)d_out;

    // workspace layout
    char* ws = (char*)d_ws;
    __bf16* x_bf   = (__bf16*)(ws);                                  // 67,108,864 B
    __bf16* weff   = (__bf16*)(ws + (size_t)67108864);               // 33,554,432 B
    __bf16* b_bf   = (__bf16*)(ws + (size_t)67108864 + 33554432);    //  2,097,152 B
    __bf16* adt_bf = (__bf16*)(ws + (size_t)67108864 + 33554432 + 2097152); // 2,097,152 B

    // 1) prep: cast B (512 blocks) + AdT transpose (256 blocks)
    prep<<<768, 256, 0, stream>>>(Bm, b_bf, A, d, adt_bf);
    // 2) fused: Weff GEMM (1024 blocks) + cast x (16384 blocks)
    weff_cast<<<1024 + 16384, 256, 0, stream>>>(b_bf, adt_bf, W, weff, x, x_bf);
    // 3) out = x_bf @ Weff^T + b
    main_gemm<<<dim3(OUT / 128, M_ROWS / 128), 256, 0, stream>>>(x_bf, weff, b, out);
}